// Round 1
// baseline (9.337 us; speedup 1.0000x reference)
//
#include <hip/hip_runtime.h>

// Closed form of the reference circuit:
//   out[s][w] = prod_{j=0..w} cos(x[s*16 + j]) * cos(weights[j])
// Derivation: RX/RY layers build a product state with per-qubit <Z> =
// cos(theta)*cos(phi); the CNOT chain maps Z_w -> Z_0...Z_w in the
// Heisenberg picture, so each expectation is a prefix product.

#define NQ 8

__global__ __launch_bounds__(256) void qru_closed_form(
    const float* __restrict__ x,
    const float* __restrict__ weights,
    float* __restrict__ out,
    int n_samples)
{
    int s = blockIdx.x * blockDim.x + threadIdx.x;
    if (s >= n_samples) return;

    // x row: 16 floats per sample, we need the first 8 (two float4 loads, 64B-aligned base)
    const float4* xp = reinterpret_cast<const float4*>(x + (size_t)s * 16);
    float4 a0 = xp[0];
    float4 a1 = xp[1];
    float ang[NQ] = {a0.x, a0.y, a0.z, a0.w, a1.x, a1.y, a1.z, a1.w};

    // weights reads are wave-uniform -> scalar loads; cos is cheap VALU.
    float prod = 1.0f;
    float ev[NQ];
#pragma unroll
    for (int j = 0; j < NQ; ++j) {
        prod *= __cosf(ang[j]) * __cosf(weights[j]);
        ev[j] = prod;
    }

    float4* op = reinterpret_cast<float4*>(out + (size_t)s * NQ);
    op[0] = make_float4(ev[0], ev[1], ev[2], ev[3]);
    op[1] = make_float4(ev[4], ev[5], ev[6], ev[7]);
}

extern "C" void kernel_launch(void* const* d_in, const int* in_sizes, int n_in,
                              void* d_out, int out_size, void* d_ws, size_t ws_size,
                              hipStream_t stream)
{
    const float* x = (const float*)d_in[0];        // (256,128,16) f32
    const float* weights = (const float*)d_in[1];  // (8,) f32
    float* out = (float*)d_out;                    // (256,128,8) f32

    int n_samples = out_size / NQ;                 // 32768
    int block = 256;
    int grid = (n_samples + block - 1) / block;    // 128
    qru_closed_form<<<grid, block, 0, stream>>>(x, weights, out, n_samples);
}